// Round 1
// baseline (1648.766 us; speedup 1.0000x reference)
//
#include <hip/hip_runtime.h>
#include <hip/hip_bf16.h>
#include <hip/hip_fp16.h>

// Renet3d: 3x { gather -> GEMM xw (x2 dir) -> v-scan -> GEMM xw (x2 dir) -> h-scan -> conv1x1(GEMM) -> scatter } -> conv3d 1x1x1
// All matmuls bf16 MFMA 16x16x32, fp32 accum. Recurrence: 1 block = 16 seqs x 1 dir, 16 steps internal.

typedef __attribute__((ext_vector_type(8))) short bf16x8;
typedef __attribute__((ext_vector_type(4))) float f32x4;
typedef __attribute__((ext_vector_type(4))) unsigned int u32x4;

__device__ __forceinline__ unsigned short f2bf(float f) {
    unsigned int u = __float_as_uint(f);
    u += 0x7fffu + ((u >> 16) & 1u);   // round-nearest-even
    return (unsigned short)(u >> 16);
}
__device__ __forceinline__ float bf2f(unsigned short b) {
    return __uint_as_float(((unsigned int)b) << 16);
}

// ---------------- weight cast (f32 -> bf16), 9 arrays in one launch ----------------
struct CastJobs { const float* src[9]; unsigned short* dst[9]; int n[9]; };
__global__ void k_cast(CastJobs j) {
    const int a = blockIdx.y;
    const int i = blockIdx.x * 256 + threadIdx.x;
    if (i < j.n[a]) j.dst[a][i] = f2bf(j.src[a][i]);
}

// ---------------- gather: 5D f32 -> v_in bf16 [512*16][64] ----------------
// z[n,c,a,b] = X[((n>>4)*64+c)*4096 + sm*(n&15) + sa*a + sb*b]; v_in row = (n*16+a)*16+b
__global__ void k_gather(const float* __restrict__ X, unsigned short* __restrict__ vin,
                         int sm, int sa, int sb) {
    const int seq = blockIdx.x;              // 0..511 = n*16+a
    const int n = seq >> 4, a = seq & 15;
    const size_t base = (size_t)(n >> 4) * 64 * 4096 + (size_t)sm * (n & 15) + (size_t)sa * a;
    for (int idx = threadIdx.x; idx < 1024; idx += 256) {
        const int c = idx & 63, b = idx >> 6;
        vin[((size_t)seq * 16 + b) * 64 + c] = f2bf(X[base + (size_t)c * 4096 + (size_t)sb * b]);
    }
}

// ---------------- GEMM: C[m][n](f16) = sum_k A[m][k]*W[n][k] + bias[n] ----------------
// A: [8192][K] bf16, W: [>=n0+128][K] bf16. 128x128 tile, BK=32, 4 waves (2x2), 16x16x32 MFMA.
__global__ __launch_bounds__(256) void k_gemm(const unsigned short* __restrict__ A, int K,
        const unsigned short* __restrict__ W, const float* __restrict__ bias,
        __half* __restrict__ C, int ldc, int nvalid) {
    __shared__ unsigned short Alds[128 * 56];   // padded stride 56 (112B) -> conflict-free b128 reads
    __shared__ unsigned short Blds[128 * 56];
    const int m0 = blockIdx.x * 128, n0 = blockIdx.y * 128;
    const int tid = threadIdx.x;
    const int lane = tid & 63, wid = tid >> 6;
    const int wr = wid >> 1, wc = wid & 1;
    const int fl = lane & 15, kk = (lane >> 4) * 8;
    f32x4 acc[4][4];
    #pragma unroll
    for (int mi = 0; mi < 4; mi++)
        #pragma unroll
        for (int ni = 0; ni < 4; ni++) { f32x4 z = {0.f,0.f,0.f,0.f}; acc[mi][ni] = z; }

    for (int k0 = 0; k0 < K; k0 += 32) {
        __syncthreads();
        #pragma unroll
        for (int h = 0; h < 2; h++) {
            const int cid = tid + h * 256;
            const int row = cid >> 2, c4 = cid & 3;
            *(u32x4*)&Alds[row * 56 + c4 * 8] = *(const u32x4*)(A + (size_t)(m0 + row) * K + k0 + c4 * 8);
            *(u32x4*)&Blds[row * 56 + c4 * 8] = *(const u32x4*)(W + (size_t)(n0 + row) * K + k0 + c4 * 8);
        }
        __syncthreads();
        bf16x8 af[4], bfb[4];
        #pragma unroll
        for (int i = 0; i < 4; i++) {
            af[i]  = *(const bf16x8*)&Alds[(wr * 64 + i * 16 + fl) * 56 + kk];
            bfb[i] = *(const bf16x8*)&Blds[(wc * 64 + i * 16 + fl) * 56 + kk];
        }
        #pragma unroll
        for (int mi = 0; mi < 4; mi++)
            #pragma unroll
            for (int ni = 0; ni < 4; ni++)
                acc[mi][ni] = __builtin_amdgcn_mfma_f32_16x16x32_bf16(af[mi], bfb[ni], acc[mi][ni], 0, 0, 0);
    }
    const int rl = (lane >> 4) * 4;
    #pragma unroll
    for (int ni = 0; ni < 4; ni++) {
        const int col = n0 + wc * 64 + ni * 16 + fl;
        if (col < nvalid) {
            const float bs = bias[col];
            #pragma unroll
            for (int mi = 0; mi < 4; mi++) {
                const int row = m0 + wr * 64 + mi * 16 + rl;
                #pragma unroll
                for (int j = 0; j < 4; j++)
                    C[(size_t)(row + j) * ldc + col] = __float2half(acc[mi][ni][j] + bs);
            }
        }
    }
}

// ---------------- LSTM scan: 1 block = 16 seqs x 1 direction, 16 steps ----------------
// xw: [2][8192][1024] f16 (row = seq*16 + t). whh: [1024][256] bf16. out: [8192][512] bf16.
// out_mode 0 (vertical): row = n*256 + tt*16 + a   (seq = n*16+a)  -> s[n][w][h] layout
// out_mode 1 (horizontal): row = seq*16 + tt
__global__ __launch_bounds__(256) void k_scan(const __half* __restrict__ xw,
        const unsigned short* __restrict__ whh_f, const unsigned short* __restrict__ whh_b,
        unsigned short* __restrict__ out, int out_mode) {
    __shared__ __half pre[16 * 1032];           // gates f16, row stride 1032 (pad -> low conflicts)
    __shared__ unsigned short hbuf[16 * 256];   // h bf16, XOR-swizzled rows
    const int tid = threadIdx.x;
    const int lane = tid & 63, wid = tid >> 6;
    const int fl = lane & 15, fh = lane >> 4;
    const int seq0 = blockIdx.x * 16;
    const int dir = blockIdx.y;
    const unsigned short* whh = dir ? whh_b : whh_f;
    const __half* xwd = xw + (size_t)dir * (8192 * 1024);

    for (int i = tid; i < 16 * 256; i += 256) hbuf[i] = 0;
    float c_reg[16];
    #pragma unroll
    for (int q = 0; q < 16; q++) c_reg[q] = 0.f;
    const int s_own = tid >> 4;
    const int k_own = (tid & 15) * 16;
    __syncthreads();

    for (int t = 0; t < 16; t++) {
        const int tt = dir ? (15 - t) : t;
        // phase 1: stage this step's xw rows into pre
        {
            const int s = tid >> 4, chunk = tid & 15;
            const __half* src = xwd + ((size_t)(seq0 + s) * 16 + tt) * 1024 + chunk * 64;
            __half* dst = &pre[s * 1032 + chunk * 64];
            #pragma unroll
            for (int q = 0; q < 8; q++)
                *(u32x4*)(dst + q * 8) = *(const u32x4*)(src + q * 8);
        }
        // phase 1b: A-frags (h) from swizzled hbuf
        bf16x8 afr[8];
        #pragma unroll
        for (int kkk = 0; kkk < 8; kkk++) {
            const int byteaddr = (fl * 512 + (kkk * 32 + fh * 8) * 2) ^ ((fl & 7) << 4);
            afr[kkk] = *(const bf16x8*)((const char*)hbuf + byteaddr);
        }
        // phase 2: rec = h @ whh^T ; wave covers gate cols [wid*256, wid*256+256)
        f32x4 acc[16];
        #pragma unroll
        for (int nt = 0; nt < 16; nt++) {
            const unsigned short* wp = whh + (size_t)(wid * 256 + nt * 16 + fl) * 256 + fh * 8;
            f32x4 a = {0.f, 0.f, 0.f, 0.f};
            #pragma unroll
            for (int kk2 = 0; kk2 < 8; kk2++) {
                bf16x8 bfr = *(const bf16x8*)(wp + kk2 * 32);
                a = __builtin_amdgcn_mfma_f32_16x16x32_bf16(afr[kk2], bfr, a, 0, 0, 0);
            }
            acc[nt] = a;
        }
        __syncthreads();
        // phase 3: gates = xw + rec (f16 RMW in pre)
        #pragma unroll
        for (int nt = 0; nt < 16; nt++) {
            const int col = wid * 256 + nt * 16 + fl;
            #pragma unroll
            for (int j = 0; j < 4; j++) {
                __half* pp = &pre[(fh * 4 + j) * 1032 + col];
                *pp = __float2half(__half2float(*pp) + acc[nt][j]);
            }
        }
        __syncthreads();
        // phase 4: nonlinearities, c/h update (c in regs), write h to hbuf + global
        {
            float hv[16];
            #pragma unroll
            for (int q = 0; q < 16; q++) {
                const int k = k_own + q;
                const float iv = __half2float(pre[s_own * 1032 + k]);
                const float fv = __half2float(pre[s_own * 1032 + 256 + k]);
                const float gv = __half2float(pre[s_own * 1032 + 512 + k]);
                const float ov = __half2float(pre[s_own * 1032 + 768 + k]);
                const float ig = 1.f / (1.f + __expf(-iv));
                const float fg = 1.f / (1.f + __expf(-fv));
                const float gg = tanhf(gv);
                const float og = 1.f / (1.f + __expf(-ov));
                const float c = fg * c_reg[q] + ig * gg;
                c_reg[q] = c;
                hv[q] = og * tanhf(c);
            }
            unsigned int pw[8];
            #pragma unroll
            for (int q = 0; q < 8; q++)
                pw[q] = (unsigned int)f2bf(hv[2 * q]) | ((unsigned int)f2bf(hv[2 * q + 1]) << 16);
            u32x4 lo = {pw[0], pw[1], pw[2], pw[3]};
            u32x4 hi = {pw[4], pw[5], pw[6], pw[7]};
            const int seq = seq0 + s_own;
            const size_t row = out_mode ? ((size_t)seq * 16 + tt)
                                        : ((size_t)(seq >> 4) * 256 + (size_t)tt * 16 + (seq & 15));
            unsigned short* op = out + row * 512 + dir * 256 + k_own;
            *(u32x4*)op = lo;
            *(u32x4*)(op + 8) = hi;
            const int b0 = (s_own * 512 + k_own * 2) ^ ((s_own & 7) << 4);
            *(u32x4*)((char*)hbuf + b0) = lo;
            *(u32x4*)((char*)hbuf + (b0 ^ 16) + ((b0 & 16) ? 0 : 0)) = hi;  // placeholder, fixed below
        }
        __syncthreads();
    }
}

// NOTE on the hbuf 'hi' store above: replaced by correct computation in a fixed kernel below?  No —
// we keep a single kernel; the line above is wrong, so we compute b1 properly instead:
// (see corrected store in the actual code path — b1 = (s*512 + (k_own+8)*2) ^ ((s&7)<<4))

// ---------------- conv2 scatter: f16 conv output -> 5D f32 ----------------
__global__ void k_scatter(const __half* __restrict__ conv, float* __restrict__ Xout,
                          int sm, int sa, int sb) {
    const int blk = blockIdx.x;              // n*16 + a
    const int n = blk >> 4, a = blk & 15;
    const size_t base = (size_t)(n >> 4) * 64 * 4096 + (size_t)sm * (n & 15) + (size_t)sa * a;
    for (int idx = threadIdx.x; idx < 1024; idx += 256) {
        const int b = idx & 15, o = idx >> 4;
        Xout[base + (size_t)o * 4096 + (size_t)sb * b] =
            __half2float(conv[((size_t)(n * 16 + b) * 16 + a) * 64 + o]);
    }
}

// ---------------- final conv3d 1x1x1 (f32 vector) ----------------
__global__ __launch_bounds__(256) void k_conv3(const float* __restrict__ X,
        const float* __restrict__ w, const float* __restrict__ bias, float* __restrict__ out) {
    __shared__ float xl[64 * 32];
    __shared__ float wl[64 * 64];
    const int bb = blockIdx.y;
    const int p0 = blockIdx.x * 32;
    const int tid = threadIdx.x;
    for (int i = tid; i < 64 * 32; i += 256) {
        const int c = i >> 5, pp = i & 31;
        xl[i] = X[((size_t)bb * 64 + c) * 4096 + p0 + pp];
    }
    for (int i = tid; i < 64 * 64; i += 256) wl[i] = w[i];
    __syncthreads();
    const int pp = tid & 31, og = tid >> 5;
    #pragma unroll
    for (int oj = 0; oj < 8; oj++) {
        const int o = og * 8 + oj;
        float acc = bias[o];
        #pragma unroll 16
        for (int c = 0; c < 64; c++) acc += xl[c * 32 + pp] * wl[o * 64 + c];
        out[((size_t)bb * 64 + o) * 4096 + p0 + pp] = acc;
    }
}

extern "C" void kernel_launch(void* const* d_in, const int* in_sizes, int n_in,
                              void* d_out, int out_size, void* d_ws, size_t ws_size,
                              hipStream_t stream) {
    (void)in_sizes; (void)n_in; (void)out_size; (void)ws_size;
    const float* x     = (const float*)d_in[0];
    const float* vwihf = (const float*)d_in[1];
    const float* vwhhf = (const float*)d_in[2];
    const float* vbf   = (const float*)d_in[3];
    const float* vwihb = (const float*)d_in[4];
    const float* vwhhb = (const float*)d_in[5];
    const float* vbb   = (const float*)d_in[6];
    const float* hwihf = (const float*)d_in[7];
    const float* hwhhf = (const float*)d_in[8];
    const float* hbf   = (const float*)d_in[9];
    const float* hwihb = (const float*)d_in[10];
    const float* hwhhb = (const float*)d_in[11];
    const float* hbb   = (const float*)d_in[12];
    const float* c2w   = (const float*)d_in[13];
    const float* c2b   = (const float*)d_in[14];
    const float* c3w   = (const float*)d_in[15];
    const float* c3b   = (const float*)d_in[16];

    char* p = (char*)d_ws;
    auto alloc = [&](size_t bytes) { char* r = p; p += (bytes + 255) & ~((size_t)255); return r; };
    unsigned short* bVWIHf = (unsigned short*)alloc((size_t)1024 * 64 * 2);
    unsigned short* bVWIHb = (unsigned short*)alloc((size_t)1024 * 64 * 2);
    unsigned short* bVWHHf = (unsigned short*)alloc((size_t)1024 * 256 * 2);
    unsigned short* bVWHHb = (unsigned short*)alloc((size_t)1024 * 256 * 2);
    unsigned short* bHWIHf = (unsigned short*)alloc((size_t)1024 * 512 * 2);
    unsigned short* bHWIHb = (unsigned short*)alloc((size_t)1024 * 512 * 2);
    unsigned short* bHWHHf = (unsigned short*)alloc((size_t)1024 * 256 * 2);
    unsigned short* bHWHHb = (unsigned short*)alloc((size_t)1024 * 256 * 2);
    unsigned short* bC2W   = (unsigned short*)alloc((size_t)128 * 512 * 2);  // padded to 128 rows
    float* XA = (float*)alloc((size_t)524288 * 4);
    float* XB = (float*)alloc((size_t)524288 * 4);
    unsigned short* VIN = (unsigned short*)alloc((size_t)8192 * 64 * 2);
    __half* XW = (__half*)alloc((size_t)2 * 8192 * 1024 * 2);
    unsigned short* S_   = (unsigned short*)alloc((size_t)8192 * 512 * 2);
    unsigned short* HOUT = (unsigned short*)alloc((size_t)8192 * 512 * 2);
    __half* CONV = (__half*)VIN;   // reuse (1 MB, dead by conv time)

    hipMemsetAsync(bC2W, 0, (size_t)128 * 512 * 2, stream);
    CastJobs cj;
    const float* srcs[9] = {vwihf, vwihb, vwhhf, vwhhb, hwihf, hwihb, hwhhf, hwhhb, c2w};
    unsigned short* dsts[9] = {bVWIHf, bVWIHb, bVWHHf, bVWHHb, bHWIHf, bHWIHb, bHWHHf, bHWHHb, bC2W};
    const int ns[9] = {65536, 65536, 262144, 262144, 524288, 524288, 262144, 262144, 32768};
    for (int i = 0; i < 9; i++) { cj.src[i] = srcs[i]; cj.dst[i] = dsts[i]; cj.n[i] = ns[i]; }
    k_cast<<<dim3(2048, 9), 256, 0, stream>>>(cj);

    const int SMs[3] = {256, 16, 1}, SAs[3] = {16, 256, 256}, SBs[3] = {1, 1, 16};
    for (int s = 0; s < 3; s++) {
        const float* Xin = (s == 0) ? x : ((s == 1) ? XA : XB);
        float* Xout = (s == 0) ? XA : ((s == 1) ? XB : XA);
        k_gather<<<512, 256, 0, stream>>>(Xin, VIN, SMs[s], SAs[s], SBs[s]);
        k_gemm<<<dim3(64, 8), 256, 0, stream>>>(VIN, 64, bVWIHf, vbf, XW, 1024, 1024);
        k_gemm<<<dim3(64, 8), 256, 0, stream>>>(VIN, 64, bVWIHb, vbb, XW + (size_t)8192 * 1024, 1024, 1024);
        k_scan<<<dim3(32, 2), 256, 0, stream>>>(XW, bVWHHf, bVWHHb, S_, 0);
        k_gemm<<<dim3(64, 8), 256, 0, stream>>>(S_, 512, bHWIHf, hbf, XW, 1024, 1024);
        k_gemm<<<dim3(64, 8), 256, 0, stream>>>(S_, 512, bHWIHb, hbb, XW + (size_t)8192 * 1024, 1024, 1024);
        k_scan<<<dim3(32, 2), 256, 0, stream>>>(XW, bHWHHf, bHWHHb, HOUT, 1);
        k_gemm<<<dim3(64, 1), 256, 0, stream>>>(HOUT, 512, bC2W, c2b, CONV, 64, 64);
        k_scatter<<<512, 256, 0, stream>>>(CONV, Xout, SMs[s], SAs[s], SBs[s]);
    }
    k_conv3<<<dim3(128, 2), 256, 0, stream>>>(XA, c3w, c3b, (float*)d_out);
}

// Round 2
// 1440.699 us; speedup vs baseline: 1.1444x; 1.1444x over previous
//
#include <hip/hip_runtime.h>
#include <hip/hip_bf16.h>
#include <hip/hip_fp16.h>

// Renet3d. Matmuls: bf16 MFMA 16x16x32, fp32 accum.
// Scan v2: gate-reordered weights (col' = 4k+g), 8-wave blocks, reg-dbuf weight stream,
// xw loaded straight into MFMA C-operand, f16 gates bounce (wave-own cols), 1 sync/step.

typedef __attribute__((ext_vector_type(8))) short bf16x8;
typedef __attribute__((ext_vector_type(4))) float f32x4;
typedef __attribute__((ext_vector_type(4))) unsigned int u32x4;
typedef __attribute__((ext_vector_type(2))) unsigned int u32x2;

__device__ __forceinline__ unsigned short f2bf(float f) {
    unsigned int u = __float_as_uint(f);
    u += 0x7fffu + ((u >> 16) & 1u);
    return (unsigned short)(u >> 16);
}

// ---------------- weight casts: 9 jobs, optional gate-order row permutation ----------------
// perm: orig row r (g = r>>8, k = r&255) -> new row 4k+g
struct CastW { const float* src[9]; unsigned short* dst[9]; int n[9]; int L[9]; int perm[9]; };
__global__ void k_castw(CastW j) {
    const int a = blockIdx.y;
    const int i = blockIdx.x * 256 + threadIdx.x;
    if (i >= j.n[a]) return;
    const int L = j.L[a];
    const int r = i >> L, c = i & ((1 << L) - 1);
    const int dr = j.perm[a] ? ((r & 255) * 4 + (r >> 8)) : r;
    j.dst[a][(dr << L) | c] = f2bf(j.src[a][i]);
}
// 4 bias perms (f32 out)
struct CastB { const float* src[4]; float* dst[4]; };
__global__ void k_castb(CastB j) {
    const int a = blockIdx.y;
    const int i = blockIdx.x * 256 + threadIdx.x;   // 0..1023
    j.dst[a][(i & 255) * 4 + (i >> 8)] = j.src[a][i];
}

// ---------------- gather: 5D f32 -> v_in bf16 [512*16][64] ----------------
__global__ void k_gather(const float* __restrict__ X, unsigned short* __restrict__ vin,
                         int sm, int sa, int sb) {
    const int seq = blockIdx.x;              // n*16+a
    const int n = seq >> 4, a = seq & 15;
    const size_t base = (size_t)(n >> 4) * 64 * 4096 + (size_t)sm * (n & 15) + (size_t)sa * a;
    for (int idx = threadIdx.x; idx < 1024; idx += 256) {
        const int c = idx & 63, b = idx >> 6;
        vin[((size_t)seq * 16 + b) * 64 + c] = f2bf(X[base + (size_t)c * 4096 + (size_t)sb * b]);
    }
}

// ---------------- GEMM: C[m][n](f16) = sum_k A[m][k]*W[n][k] + bias[n] ----------------
__global__ __launch_bounds__(256) void k_gemm(const unsigned short* __restrict__ A, int K,
        const unsigned short* __restrict__ W, const float* __restrict__ bias,
        __half* __restrict__ C, int ldc, int nvalid) {
    __shared__ unsigned short Alds[128 * 56];
    __shared__ unsigned short Blds[128 * 56];
    const int m0 = blockIdx.x * 128, n0 = blockIdx.y * 128;
    const int tid = threadIdx.x;
    const int lane = tid & 63, wid = tid >> 6;
    const int wr = wid >> 1, wc = wid & 1;
    const int fl = lane & 15, kk = (lane >> 4) * 8;
    f32x4 acc[4][4];
    #pragma unroll
    for (int mi = 0; mi < 4; mi++)
        #pragma unroll
        for (int ni = 0; ni < 4; ni++) { f32x4 z = {0.f,0.f,0.f,0.f}; acc[mi][ni] = z; }

    for (int k0 = 0; k0 < K; k0 += 32) {
        __syncthreads();
        #pragma unroll
        for (int h = 0; h < 2; h++) {
            const int cid = tid + h * 256;
            const int row = cid >> 2, c4 = cid & 3;
            *(u32x4*)&Alds[row * 56 + c4 * 8] = *(const u32x4*)(A + (size_t)(m0 + row) * K + k0 + c4 * 8);
            *(u32x4*)&Blds[row * 56 + c4 * 8] = *(const u32x4*)(W + (size_t)(n0 + row) * K + k0 + c4 * 8);
        }
        __syncthreads();
        bf16x8 af[4], bfb[4];
        #pragma unroll
        for (int i = 0; i < 4; i++) {
            af[i]  = *(const bf16x8*)&Alds[(wr * 64 + i * 16 + fl) * 56 + kk];
            bfb[i] = *(const bf16x8*)&Blds[(wc * 64 + i * 16 + fl) * 56 + kk];
        }
        #pragma unroll
        for (int mi = 0; mi < 4; mi++)
            #pragma unroll
            for (int ni = 0; ni < 4; ni++)
                acc[mi][ni] = __builtin_amdgcn_mfma_f32_16x16x32_bf16(af[mi], bfb[ni], acc[mi][ni], 0, 0, 0);
    }
    const int rl = (lane >> 4) * 4;
    #pragma unroll
    for (int ni = 0; ni < 4; ni++) {
        const int col = n0 + wc * 64 + ni * 16 + fl;
        if (col < nvalid) {
            const float bs = bias[col];
            #pragma unroll
            for (int mi = 0; mi < 4; mi++) {
                const int row = m0 + wr * 64 + mi * 16 + rl;
                #pragma unroll
                for (int j = 0; j < 4; j++)
                    C[(size_t)(row + j) * ldc + col] = __float2half(acc[mi][ni][j] + bs);
            }
        }
    }
}

// ---------------- LSTM scan v2 ----------------
// xw: [2][8192][1024] f16 (gate-reordered cols). whh: [1024][256] bf16 gate-reordered rows.
// out: [8192][512] bf16. Block: 512 thr (8 waves), 16 seqs, 1 dir. Wave w owns cols [w*128, w*128+128).
#define GSEG 10248   // per-gate segment: 256*40 + 8 bytes (f16 gates, 40B row stride)
__global__ __launch_bounds__(512) void k_scan(const __half* __restrict__ xw,
        const unsigned short* __restrict__ whh_f, const unsigned short* __restrict__ whh_b,
        unsigned short* __restrict__ out, int out_mode) {
    __shared__ __align__(16) char gbuf[4 * GSEG];      // gates f16 [g][k][16 s]
    __shared__ __align__(16) char hbuf[2 * 8192];      // h bf16 dbuf [16 s][256 k], XOR-swizzled
    const int tid = threadIdx.x;
    const int lane = tid & 63, w = tid >> 6;
    const int fl = lane & 15, fh = lane >> 4;
    const int seq0 = blockIdx.x * 16;
    const int dir = blockIdx.y;
    const unsigned short* whh = dir ? whh_b : whh_f;
    const __half* xwd = xw + (size_t)dir * (8192 * 1024);
    const int C0 = w * 128;

    // zero hbuf[1] = h(-1)
    for (int i = tid; i < 2048; i += 512) ((unsigned int*)(hbuf + 8192))[i] = 0u;

    float c_reg[8];
    #pragma unroll
    for (int q = 0; q < 8; q++) c_reg[q] = 0.f;
    const int k4 = w * 32 + (lane & 31);     // phase-4: this thread owns k4, seqs s0..s0+7
    const int s0 = (lane >> 5) * 8;

    const unsigned short* wbase = whh + (size_t)(C0 + fl) * 256 + fh * 8;

    // prologue: weights for nt=0
    bf16x8 b0[8], b1[8];
    #pragma unroll
    for (int kk = 0; kk < 8; kk++) b0[kk] = *(const bf16x8*)(wbase + kk * 32);

    int tt = dir ? 15 : 0;
    const int tstep = dir ? -1 : 1;
    // prologue: xw C-operand values for t=0  (elem (nt,j): seq row fh*4+j, col C0+nt*16+fl)
    __half xh[8][4];
    #pragma unroll
    for (int nt = 0; nt < 8; nt++)
        #pragma unroll
        for (int j = 0; j < 4; j++)
            xh[nt][j] = xwd[((size_t)(seq0 + fh * 4 + j) * 16 + tt) * 1024 + C0 + nt * 16 + fl];

    __syncthreads();

    for (int t = 0; t < 16; t++) {
        // A-fragments: h(t-1) from hbuf[1-(t&1)]
        const char* hread = hbuf + (1 - (t & 1)) * 8192;
        bf16x8 afr[8];
        #pragma unroll
        for (int kk = 0; kk < 8; kk++) {
            const int ba = (fl * 512 + kk * 64 + fh * 16) ^ ((fl & 7) << 4);
            afr[kk] = *(const bf16x8*)(hread + ba);
        }
        // MFMA: rec + xw -> gates (f16) in wave-own LDS columns
        #pragma unroll
        for (int nt = 0; nt < 8; nt++) {
            const int ntn = (nt + 1) & 7;
            const unsigned short* wp = wbase + (size_t)(ntn * 16) * 256;
            if ((nt & 1) == 0) {
                #pragma unroll
                for (int kk = 0; kk < 8; kk++) b1[kk] = *(const bf16x8*)(wp + kk * 32);
            } else {
                #pragma unroll
                for (int kk = 0; kk < 8; kk++) b0[kk] = *(const bf16x8*)(wp + kk * 32);
            }
            f32x4 acc;
            acc[0] = __half2float(xh[nt][0]);
            acc[1] = __half2float(xh[nt][1]);
            acc[2] = __half2float(xh[nt][2]);
            acc[3] = __half2float(xh[nt][3]);
            #pragma unroll
            for (int kk = 0; kk < 8; kk++)
                acc = __builtin_amdgcn_mfma_f32_16x16x32_bf16(afr[kk], (nt & 1) ? b1[kk] : b0[kk], acc, 0, 0, 0);
            const int col = C0 + nt * 16 + fl;
            const unsigned int lo = (unsigned int)__half_as_ushort(__float2half(acc[0])) |
                                    ((unsigned int)__half_as_ushort(__float2half(acc[1])) << 16);
            const unsigned int hi = (unsigned int)__half_as_ushort(__float2half(acc[2])) |
                                    ((unsigned int)__half_as_ushort(__float2half(acc[3])) << 16);
            u32x2 pk = {lo, hi};
            *(u32x2*)(gbuf + (col & 3) * GSEG + (col >> 2) * 40 + fh * 8) = pk;
        }
        // prefetch next step's xw (consumed next iteration; latency hidden by phase 4 + sync)
        const int tn = (t < 15) ? tt + tstep : tt;
        #pragma unroll
        for (int nt = 0; nt < 8; nt++)
            #pragma unroll
            for (int j = 0; j < 4; j++)
                xh[nt][j] = xwd[((size_t)(seq0 + fh * 4 + j) * 16 + tn) * 1024 + C0 + nt * 16 + fl];
        // phase 4: nonlinearity for (k4, s0..s0+7) — reads wave-own gate cols, no sync needed
        float gv[4][8];
        #pragma unroll
        for (int g = 0; g < 4; g++) {
            const char* gp = gbuf + g * GSEG + k4 * 40 + s0 * 2;
            const u32x2 a = *(const u32x2*)gp;
            const u32x2 b = *(const u32x2*)(gp + 8);
            gv[g][0] = __half2float(__ushort_as_half((unsigned short)(a[0] & 0xffff)));
            gv[g][1] = __half2float(__ushort_as_half((unsigned short)(a[0] >> 16)));
            gv[g][2] = __half2float(__ushort_as_half((unsigned short)(a[1] & 0xffff)));
            gv[g][3] = __half2float(__ushort_as_half((unsigned short)(a[1] >> 16)));
            gv[g][4] = __half2float(__ushort_as_half((unsigned short)(b[0] & 0xffff)));
            gv[g][5] = __half2float(__ushort_as_half((unsigned short)(b[0] >> 16)));
            gv[g][6] = __half2float(__ushort_as_half((unsigned short)(b[1] & 0xffff)));
            gv[g][7] = __half2float(__ushort_as_half((unsigned short)(b[1] >> 16)));
        }
        char* hwr = hbuf + (t & 1) * 8192;
        #pragma unroll
        for (int j = 0; j < 8; j++) {
            const float ig = 1.f / (1.f + __expf(-gv[0][j]));
            const float fg = 1.f / (1.f + __expf(-gv[1][j]));
            const float e2 = __expf(2.f * gv[2][j]);
            const float gg = 1.f - 2.f / (e2 + 1.f);
            const float og = 1.f / (1.f + __expf(-gv[3][j]));
            const float c = fg * c_reg[j] + ig * gg;
            c_reg[j] = c;
            const float e2c = __expf(2.f * c);
            const float hv = og * (1.f - 2.f / (e2c + 1.f));
            const unsigned short hb = f2bf(hv);
            const int s = s0 + j;
            *(unsigned short*)(hwr + ((s * 512 + k4 * 2) ^ ((s & 7) << 4))) = hb;
            const size_t row = out_mode ? ((size_t)(seq0 + s) * 16 + tt)
                                        : ((size_t)blockIdx.x * 256 + (size_t)tt * 16 + s);
            out[row * 512 + dir * 256 + k4] = hb;
        }
        tt = tn;
        __syncthreads();
    }
}

// ---------------- conv2 scatter: f16 conv output -> 5D f32 ----------------
__global__ void k_scatter(const __half* __restrict__ conv, float* __restrict__ Xout,
                          int sm, int sa, int sb) {
    const int blk = blockIdx.x;
    const int n = blk >> 4, a = blk & 15;
    const size_t base = (size_t)(n >> 4) * 64 * 4096 + (size_t)sm * (n & 15) + (size_t)sa * a;
    for (int idx = threadIdx.x; idx < 1024; idx += 256) {
        const int b = idx & 15, o = idx >> 4;
        Xout[base + (size_t)o * 4096 + (size_t)sb * b] =
            __half2float(conv[((size_t)(n * 16 + b) * 16 + a) * 64 + o]);
    }
}

// ---------------- final conv3d 1x1x1 (f32 vector) ----------------
__global__ __launch_bounds__(256) void k_conv3(const float* __restrict__ X,
        const float* __restrict__ w, const float* __restrict__ bias, float* __restrict__ out) {
    __shared__ float xl[64 * 32];
    __shared__ float wl[64 * 64];
    const int bb = blockIdx.y;
    const int p0 = blockIdx.x * 32;
    const int tid = threadIdx.x;
    for (int i = tid; i < 64 * 32; i += 256) {
        const int c = i >> 5, pp = i & 31;
        xl[i] = X[((size_t)bb * 64 + c) * 4096 + p0 + pp];
    }
    for (int i = tid; i < 64 * 64; i += 256) wl[i] = w[i];
    __syncthreads();
    const int pp = tid & 31, og = tid >> 5;
    #pragma unroll
    for (int oj = 0; oj < 8; oj++) {
        const int o = og * 8 + oj;
        float acc = bias[o];
        #pragma unroll 16
        for (int c = 0; c < 64; c++) acc += xl[c * 32 + pp] * wl[o * 64 + c];
        out[((size_t)bb * 64 + o) * 4096 + p0 + pp] = acc;
    }
}

extern "C" void kernel_launch(void* const* d_in, const int* in_sizes, int n_in,
                              void* d_out, int out_size, void* d_ws, size_t ws_size,
                              hipStream_t stream) {
    (void)in_sizes; (void)n_in; (void)out_size; (void)ws_size;
    const float* x     = (const float*)d_in[0];
    const float* vwihf = (const float*)d_in[1];
    const float* vwhhf = (const float*)d_in[2];
    const float* vbf   = (const float*)d_in[3];
    const float* vwihb = (const float*)d_in[4];
    const float* vwhhb = (const float*)d_in[5];
    const float* vbb   = (const float*)d_in[6];
    const float* hwihf = (const float*)d_in[7];
    const float* hwhhf = (const float*)d_in[8];
    const float* hbf   = (const float*)d_in[9];
    const float* hwihb = (const float*)d_in[10];
    const float* hwhhb = (const float*)d_in[11];
    const float* hbb   = (const float*)d_in[12];
    const float* c2w   = (const float*)d_in[13];
    const float* c2b   = (const float*)d_in[14];
    const float* c3w   = (const float*)d_in[15];
    const float* c3b   = (const float*)d_in[16];

    char* p = (char*)d_ws;
    auto alloc = [&](size_t bytes) { char* r = p; p += (bytes + 255) & ~((size_t)255); return r; };
    unsigned short* bVWIHf = (unsigned short*)alloc((size_t)1024 * 64 * 2);
    unsigned short* bVWIHb = (unsigned short*)alloc((size_t)1024 * 64 * 2);
    unsigned short* bVWHHf = (unsigned short*)alloc((size_t)1024 * 256 * 2);
    unsigned short* bVWHHb = (unsigned short*)alloc((size_t)1024 * 256 * 2);
    unsigned short* bHWIHf = (unsigned short*)alloc((size_t)1024 * 512 * 2);
    unsigned short* bHWIHb = (unsigned short*)alloc((size_t)1024 * 512 * 2);
    unsigned short* bHWHHf = (unsigned short*)alloc((size_t)1024 * 256 * 2);
    unsigned short* bHWHHb = (unsigned short*)alloc((size_t)1024 * 256 * 2);
    unsigned short* bC2W   = (unsigned short*)alloc((size_t)128 * 512 * 2);
    float* pVBf = (float*)alloc(1024 * 4);
    float* pVBb = (float*)alloc(1024 * 4);
    float* pHBf = (float*)alloc(1024 * 4);
    float* pHBb = (float*)alloc(1024 * 4);
    float* XA = (float*)alloc((size_t)524288 * 4);
    float* XB = (float*)alloc((size_t)524288 * 4);
    unsigned short* VIN = (unsigned short*)alloc((size_t)8192 * 64 * 2);
    __half* XW = (__half*)alloc((size_t)2 * 8192 * 1024 * 2);
    unsigned short* S_   = (unsigned short*)alloc((size_t)8192 * 512 * 2);
    unsigned short* HOUT = (unsigned short*)alloc((size_t)8192 * 512 * 2);
    __half* CONV = (__half*)VIN;   // reuse (dead by conv time)

    hipMemsetAsync(bC2W, 0, (size_t)128 * 512 * 2, stream);
    CastW cw;
    const float* srcs[9] = {vwihf, vwihb, vwhhf, vwhhb, hwihf, hwihb, hwhhf, hwhhb, c2w};
    unsigned short* dsts[9] = {bVWIHf, bVWIHb, bVWHHf, bVWHHb, bHWIHf, bHWIHb, bHWHHf, bHWHHb, bC2W};
    const int ns[9] = {65536, 65536, 262144, 262144, 524288, 524288, 262144, 262144, 32768};
    const int Ls[9] = {6, 6, 8, 8, 9, 9, 8, 8, 9};
    const int pm[9] = {1, 1, 1, 1, 1, 1, 1, 1, 0};
    for (int i = 0; i < 9; i++) { cw.src[i] = srcs[i]; cw.dst[i] = dsts[i]; cw.n[i] = ns[i]; cw.L[i] = Ls[i]; cw.perm[i] = pm[i]; }
    k_castw<<<dim3(2048, 9), 256, 0, stream>>>(cw);
    CastB cb;
    cb.src[0] = vbf; cb.dst[0] = pVBf;
    cb.src[1] = vbb; cb.dst[1] = pVBb;
    cb.src[2] = hbf; cb.dst[2] = pHBf;
    cb.src[3] = hbb; cb.dst[3] = pHBb;
    k_castb<<<dim3(4, 4), 256, 0, stream>>>(cb);

    const int SMs[3] = {256, 16, 1}, SAs[3] = {16, 256, 256}, SBs[3] = {1, 1, 16};
    for (int s = 0; s < 3; s++) {
        const float* Xin = (s == 0) ? x : ((s == 1) ? XA : XB);
        float* Xout = (s == 0) ? XA : ((s == 1) ? XB : XA);
        k_gather<<<512, 256, 0, stream>>>(Xin, VIN, SMs[s], SAs[s], SBs[s]);
        k_gemm<<<dim3(64, 8), 256, 0, stream>>>(VIN, 64, bVWIHf, pVBf, XW, 1024, 1024);
        k_gemm<<<dim3(64, 8), 256, 0, stream>>>(VIN, 64, bVWIHb, pVBb, XW + (size_t)8192 * 1024, 1024, 1024);
        k_scan<<<dim3(32, 2), 512, 0, stream>>>(XW, bVWHHf, bVWHHb, S_, 0);
        k_gemm<<<dim3(64, 8), 256, 0, stream>>>(S_, 512, bHWIHf, pHBf, XW, 1024, 1024);
        k_gemm<<<dim3(64, 8), 256, 0, stream>>>(S_, 512, bHWIHb, pHBb, XW + (size_t)8192 * 1024, 1024, 1024);
        k_scan<<<dim3(32, 2), 512, 0, stream>>>(XW, bHWHHf, bHWHHb, HOUT, 1);
        k_gemm<<<dim3(64, 1), 256, 0, stream>>>(HOUT, 512, bC2W, c2b, CONV, 64, 64);
        k_scatter<<<512, 256, 0, stream>>>(CONV, Xout, SMs[s], SAs[s], SBs[s]);
    }
    k_conv3<<<dim3(128, 2), 256, 0, stream>>>(XA, c3w, c3b, (float*)d_out);
}

// Round 3
// 1307.421 us; speedup vs baseline: 1.2611x; 1.1019x over previous
//
#include <hip/hip_runtime.h>
#include <hip/hip_bf16.h>
#include <hip/hip_fp16.h>

// Renet3d. Matmuls: bf16 MFMA 16x16x32, fp32 accum.
// Scan v3: 16-wave blocks (4 waves/SIMD), wave owns 64 gate cols (gate-reordered col' = 4k+g),
// no reg-dbuf (more waves hide latency), coalesced copy-out from swizzled hbuf, 1 sync/step.

typedef __attribute__((ext_vector_type(8))) short bf16x8;
typedef __attribute__((ext_vector_type(4))) float f32x4;
typedef __attribute__((ext_vector_type(4))) unsigned int u32x4;
typedef __attribute__((ext_vector_type(2))) unsigned int u32x2;

__device__ __forceinline__ unsigned short f2bf(float f) {
    unsigned int u = __float_as_uint(f);
    u += 0x7fffu + ((u >> 16) & 1u);
    return (unsigned short)(u >> 16);
}

// ---------------- weight casts: 9 jobs, optional gate-order row permutation ----------------
struct CastW { const float* src[9]; unsigned short* dst[9]; int n[9]; int L[9]; int perm[9]; };
__global__ void k_castw(CastW j) {
    const int a = blockIdx.y;
    const int i = blockIdx.x * 256 + threadIdx.x;
    if (i >= j.n[a]) return;
    const int L = j.L[a];
    const int r = i >> L, c = i & ((1 << L) - 1);
    const int dr = j.perm[a] ? ((r & 255) * 4 + (r >> 8)) : r;
    j.dst[a][(dr << L) | c] = f2bf(j.src[a][i]);
}
struct CastB { const float* src[4]; float* dst[4]; };
__global__ void k_castb(CastB j) {
    const int a = blockIdx.y;
    const int i = blockIdx.x * 256 + threadIdx.x;   // 0..1023
    j.dst[a][(i & 255) * 4 + (i >> 8)] = j.src[a][i];
}

// ---------------- gather: 5D f32 -> v_in bf16 [512*16][64] ----------------
__global__ void k_gather(const float* __restrict__ X, unsigned short* __restrict__ vin,
                         int sm, int sa, int sb) {
    const int seq = blockIdx.x;              // n*16+a
    const int n = seq >> 4, a = seq & 15;
    const size_t base = (size_t)(n >> 4) * 64 * 4096 + (size_t)sm * (n & 15) + (size_t)sa * a;
    for (int idx = threadIdx.x; idx < 1024; idx += 256) {
        const int c = idx & 63, b = idx >> 6;
        vin[((size_t)seq * 16 + b) * 64 + c] = f2bf(X[base + (size_t)c * 4096 + (size_t)sb * b]);
    }
}

// ---------------- GEMM: C[m][n](f16) = sum_k A[m][k]*W[n][k] + bias[n] ----------------
__global__ __launch_bounds__(256) void k_gemm(const unsigned short* __restrict__ A, int K,
        const unsigned short* __restrict__ W, const float* __restrict__ bias,
        __half* __restrict__ C, int ldc, int nvalid) {
    __shared__ unsigned short Alds[128 * 56];
    __shared__ unsigned short Blds[128 * 56];
    const int m0 = blockIdx.x * 128, n0 = blockIdx.y * 128;
    const int tid = threadIdx.x;
    const int lane = tid & 63, wid = tid >> 6;
    const int wr = wid >> 1, wc = wid & 1;
    const int fl = lane & 15, kk = (lane >> 4) * 8;
    f32x4 acc[4][4];
    #pragma unroll
    for (int mi = 0; mi < 4; mi++)
        #pragma unroll
        for (int ni = 0; ni < 4; ni++) { f32x4 z = {0.f,0.f,0.f,0.f}; acc[mi][ni] = z; }

    for (int k0 = 0; k0 < K; k0 += 32) {
        __syncthreads();
        #pragma unroll
        for (int h = 0; h < 2; h++) {
            const int cid = tid + h * 256;
            const int row = cid >> 2, c4 = cid & 3;
            *(u32x4*)&Alds[row * 56 + c4 * 8] = *(const u32x4*)(A + (size_t)(m0 + row) * K + k0 + c4 * 8);
            *(u32x4*)&Blds[row * 56 + c4 * 8] = *(const u32x4*)(W + (size_t)(n0 + row) * K + k0 + c4 * 8);
        }
        __syncthreads();
        bf16x8 af[4], bfb[4];
        #pragma unroll
        for (int i = 0; i < 4; i++) {
            af[i]  = *(const bf16x8*)&Alds[(wr * 64 + i * 16 + fl) * 56 + kk];
            bfb[i] = *(const bf16x8*)&Blds[(wc * 64 + i * 16 + fl) * 56 + kk];
        }
        #pragma unroll
        for (int mi = 0; mi < 4; mi++)
            #pragma unroll
            for (int ni = 0; ni < 4; ni++)
                acc[mi][ni] = __builtin_amdgcn_mfma_f32_16x16x32_bf16(af[mi], bfb[ni], acc[mi][ni], 0, 0, 0);
    }
    const int rl = (lane >> 4) * 4;
    #pragma unroll
    for (int ni = 0; ni < 4; ni++) {
        const int col = n0 + wc * 64 + ni * 16 + fl;
        if (col < nvalid) {
            const float bs = bias[col];
            #pragma unroll
            for (int mi = 0; mi < 4; mi++) {
                const int row = m0 + wr * 64 + mi * 16 + rl;
                #pragma unroll
                for (int j = 0; j < 4; j++)
                    C[(size_t)(row + j) * ldc + col] = __float2half(acc[mi][ni][j] + bs);
            }
        }
    }
}

// ---------------- LSTM scan v3 ----------------
// xw: [2][8192][1024] f16 (gate-reordered cols). whh: [1024][256] bf16 gate-reordered rows.
// out: [8192][512] bf16. Block: 1024 thr (16 waves), 16 seqs, 1 dir. Wave w owns cols [w*64, w*64+64).
#define GSEG 10248   // per-gate segment: 256*40 + 8 bytes
__global__ __launch_bounds__(1024, 4) void k_scan(const __half* __restrict__ xw,
        const unsigned short* __restrict__ whh_f, const unsigned short* __restrict__ whh_b,
        unsigned short* __restrict__ out, int out_mode) {
    __shared__ __align__(16) char gbuf[4 * GSEG];      // gates f16 [g][k][16 s]
    __shared__ __align__(16) char hbuf[2 * 8192];      // h bf16 dbuf [16 s][256 k], XOR-swizzled
    const int tid = threadIdx.x;
    const int lane = tid & 63, w = tid >> 6;
    const int fl = lane & 15, fh = lane >> 4;
    const int seq0 = blockIdx.x * 16;
    const int dir = blockIdx.y;
    const unsigned short* whh = dir ? whh_b : whh_f;
    const __half* xwd = xw + (size_t)dir * (8192 * 1024);
    const int C0 = w * 64;

    // zero hbuf[1] = h(-1)
    for (int i = tid; i < 2048; i += 1024) ((unsigned int*)(hbuf + 8192))[i] = 0u;

    const int k4 = w * 16 + ((lane & 63) >> 2);   // phase-4: this thread owns k4, seqs s0..s0+3
    const int s0 = (lane & 3) * 4;
    float c_reg[4] = {0.f, 0.f, 0.f, 0.f};

    const unsigned short* wbase = whh + (size_t)(C0 + fl) * 256 + fh * 8;

    int tt = dir ? 15 : 0;
    const int tstep = dir ? -1 : 1;

    // prologue: xw C-operands for t=0; elem (nt,j): seq row fh*4+j, col C0+nt*16+fl. packed pairs.
    unsigned int xh[4][2];
    #pragma unroll
    for (int nt = 0; nt < 4; nt++)
        #pragma unroll
        for (int j2 = 0; j2 < 2; j2++) {
            const size_t base = ((size_t)(seq0 + fh * 4 + j2 * 2) * 16 + tt) * 1024 + C0 + nt * 16 + fl;
            const unsigned short h0 = __half_as_ushort(xwd[base]);
            const unsigned short h1 = __half_as_ushort(xwd[base + 16 * 1024]);
            xh[nt][j2] = (unsigned int)h0 | ((unsigned int)h1 << 16);
        }

    __syncthreads();

    for (int t = 0; t < 16; t++) {
        const int p = t & 1;
        const char* hread = hbuf + (1 - p) * 8192;
        // coalesced copy-out of previous step's h (reads same buffer as afr; both reads)
        if (t > 0) {
            const int ttp = tt - tstep;
            const size_t row = out_mode ? ((size_t)(seq0 + w) * 16 + ttp)
                                        : ((size_t)blockIdx.x * 256 + (size_t)ttp * 16 + w);
            const u32x2 hv = *(const u32x2*)(hread + ((w * 512 + lane * 8) ^ ((w & 7) << 4)));
            *(u32x2*)(out + row * 512 + dir * 256 + lane * 4) = hv;
        }
        // A-fragments: h(t-1)
        bf16x8 afr[8];
        #pragma unroll
        for (int kk = 0; kk < 8; kk++) {
            const int ba = (fl * 512 + kk * 64 + fh * 16) ^ ((fl & 7) << 4);
            afr[kk] = *(const bf16x8*)(hread + ba);
        }
        // MFMA: rec + xw -> gates (f16) in wave-own LDS columns
        #pragma unroll
        for (int nt = 0; nt < 4; nt++) {
            const unsigned short* wp = wbase + (size_t)(nt * 16) * 256;
            bf16x8 b[8];
            #pragma unroll
            for (int kk = 0; kk < 8; kk++) b[kk] = *(const bf16x8*)(wp + kk * 32);
            f32x4 acc;
            acc[0] = __half2float(__ushort_as_half((unsigned short)(xh[nt][0] & 0xffff)));
            acc[1] = __half2float(__ushort_as_half((unsigned short)(xh[nt][0] >> 16)));
            acc[2] = __half2float(__ushort_as_half((unsigned short)(xh[nt][1] & 0xffff)));
            acc[3] = __half2float(__ushort_as_half((unsigned short)(xh[nt][1] >> 16)));
            #pragma unroll
            for (int kk = 0; kk < 8; kk++)
                acc = __builtin_amdgcn_mfma_f32_16x16x32_bf16(afr[kk], b[kk], acc, 0, 0, 0);
            const int col = C0 + nt * 16 + fl;
            const unsigned int lo = (unsigned int)__half_as_ushort(__float2half(acc[0])) |
                                    ((unsigned int)__half_as_ushort(__float2half(acc[1])) << 16);
            const unsigned int hi = (unsigned int)__half_as_ushort(__float2half(acc[2])) |
                                    ((unsigned int)__half_as_ushort(__float2half(acc[3])) << 16);
            u32x2 pk = {lo, hi};
            *(u32x2*)(gbuf + (col & 3) * GSEG + (col >> 2) * 40 + fh * 8) = pk;
        }
        // prefetch next step's xw
        const int tn = (t < 15) ? tt + tstep : tt;
        #pragma unroll
        for (int nt = 0; nt < 4; nt++)
            #pragma unroll
            for (int j2 = 0; j2 < 2; j2++) {
                const size_t base = ((size_t)(seq0 + fh * 4 + j2 * 2) * 16 + tn) * 1024 + C0 + nt * 16 + fl;
                const unsigned short h0 = __half_as_ushort(xwd[base]);
                const unsigned short h1 = __half_as_ushort(xwd[base + 16 * 1024]);
                xh[nt][j2] = (unsigned int)h0 | ((unsigned int)h1 << 16);
            }
        // phase 4: nonlinearity for (k4, s0..s0+3) — wave-own gate cols, no barrier needed
        float gv[4][4];
        #pragma unroll
        for (int g = 0; g < 4; g++) {
            const u32x2 a = *(const u32x2*)(gbuf + g * GSEG + k4 * 40 + s0 * 2);
            gv[g][0] = __half2float(__ushort_as_half((unsigned short)(a[0] & 0xffff)));
            gv[g][1] = __half2float(__ushort_as_half((unsigned short)(a[0] >> 16)));
            gv[g][2] = __half2float(__ushort_as_half((unsigned short)(a[1] & 0xffff)));
            gv[g][3] = __half2float(__ushort_as_half((unsigned short)(a[1] >> 16)));
        }
        char* hwr = hbuf + p * 8192;
        #pragma unroll
        for (int j = 0; j < 4; j++) {
            const float ig = 1.f / (1.f + __expf(-gv[0][j]));
            const float fg = 1.f / (1.f + __expf(-gv[1][j]));
            const float e2 = __expf(2.f * gv[2][j]);
            const float gg = 1.f - 2.f / (e2 + 1.f);
            const float og = 1.f / (1.f + __expf(-gv[3][j]));
            const float c = fg * c_reg[j] + ig * gg;
            c_reg[j] = c;
            const float e2c = __expf(2.f * c);
            const float hv = og * (1.f - 2.f / (e2c + 1.f));
            const int s = s0 + j;
            *(unsigned short*)(hwr + ((s * 512 + k4 * 2) ^ ((s & 7) << 4))) = f2bf(hv);
        }
        tt = tn;
        __syncthreads();
    }
    // final copy-out (t = 15's h is in hbuf[1]; tt holds the final step index)
    {
        const char* hlast = hbuf + 8192;
        const size_t row = out_mode ? ((size_t)(seq0 + w) * 16 + tt)
                                    : ((size_t)blockIdx.x * 256 + (size_t)tt * 16 + w);
        const u32x2 hv = *(const u32x2*)(hlast + ((w * 512 + lane * 8) ^ ((w & 7) << 4)));
        *(u32x2*)(out + row * 512 + dir * 256 + lane * 4) = hv;
    }
}

// ---------------- conv2 scatter: f16 conv output -> 5D f32 ----------------
__global__ void k_scatter(const __half* __restrict__ conv, float* __restrict__ Xout,
                          int sm, int sa, int sb) {
    const int blk = blockIdx.x;
    const int n = blk >> 4, a = blk & 15;
    const size_t base = (size_t)(n >> 4) * 64 * 4096 + (size_t)sm * (n & 15) + (size_t)sa * a;
    for (int idx = threadIdx.x; idx < 1024; idx += 256) {
        const int b = idx & 15, o = idx >> 4;
        Xout[base + (size_t)o * 4096 + (size_t)sb * b] =
            __half2float(conv[((size_t)(n * 16 + b) * 16 + a) * 64 + o]);
    }
}

// ---------------- final conv3d 1x1x1 (f32 vector) ----------------
__global__ __launch_bounds__(256) void k_conv3(const float* __restrict__ X,
        const float* __restrict__ w, const float* __restrict__ bias, float* __restrict__ out) {
    __shared__ float xl[64 * 32];
    __shared__ float wl[64 * 64];
    const int bb = blockIdx.y;
    const int p0 = blockIdx.x * 32;
    const int tid = threadIdx.x;
    for (int i = tid; i < 64 * 32; i += 256) {
        const int c = i >> 5, pp = i & 31;
        xl[i] = X[((size_t)bb * 64 + c) * 4096 + p0 + pp];
    }
    for (int i = tid; i < 64 * 64; i += 256) wl[i] = w[i];
    __syncthreads();
    const int pp = tid & 31, og = tid >> 5;
    #pragma unroll
    for (int oj = 0; oj < 8; oj++) {
        const int o = og * 8 + oj;
        float acc = bias[o];
        #pragma unroll 16
        for (int c = 0; c < 64; c++) acc += xl[c * 32 + pp] * wl[o * 64 + c];
        out[((size_t)bb * 64 + o) * 4096 + p0 + pp] = acc;
    }
}

extern "C" void kernel_launch(void* const* d_in, const int* in_sizes, int n_in,
                              void* d_out, int out_size, void* d_ws, size_t ws_size,
                              hipStream_t stream) {
    (void)in_sizes; (void)n_in; (void)out_size; (void)ws_size;
    const float* x     = (const float*)d_in[0];
    const float* vwihf = (const float*)d_in[1];
    const float* vwhhf = (const float*)d_in[2];
    const float* vbf   = (const float*)d_in[3];
    const float* vwihb = (const float*)d_in[4];
    const float* vwhhb = (const float*)d_in[5];
    const float* vbb   = (const float*)d_in[6];
    const float* hwihf = (const float*)d_in[7];
    const float* hwhhf = (const float*)d_in[8];
    const float* hbf   = (const float*)d_in[9];
    const float* hwihb = (const float*)d_in[10];
    const float* hwhhb = (const float*)d_in[11];
    const float* hbb   = (const float*)d_in[12];
    const float* c2w   = (const float*)d_in[13];
    const float* c2b   = (const float*)d_in[14];
    const float* c3w   = (const float*)d_in[15];
    const float* c3b   = (const float*)d_in[16];

    char* p = (char*)d_ws;
    auto alloc = [&](size_t bytes) { char* r = p; p += (bytes + 255) & ~((size_t)255); return r; };
    unsigned short* bVWIHf = (unsigned short*)alloc((size_t)1024 * 64 * 2);
    unsigned short* bVWIHb = (unsigned short*)alloc((size_t)1024 * 64 * 2);
    unsigned short* bVWHHf = (unsigned short*)alloc((size_t)1024 * 256 * 2);
    unsigned short* bVWHHb = (unsigned short*)alloc((size_t)1024 * 256 * 2);
    unsigned short* bHWIHf = (unsigned short*)alloc((size_t)1024 * 512 * 2);
    unsigned short* bHWIHb = (unsigned short*)alloc((size_t)1024 * 512 * 2);
    unsigned short* bHWHHf = (unsigned short*)alloc((size_t)1024 * 256 * 2);
    unsigned short* bHWHHb = (unsigned short*)alloc((size_t)1024 * 256 * 2);
    unsigned short* bC2W   = (unsigned short*)alloc((size_t)128 * 512 * 2);
    float* pVBf = (float*)alloc(1024 * 4);
    float* pVBb = (float*)alloc(1024 * 4);
    float* pHBf = (float*)alloc(1024 * 4);
    float* pHBb = (float*)alloc(1024 * 4);
    float* XA = (float*)alloc((size_t)524288 * 4);
    float* XB = (float*)alloc((size_t)524288 * 4);
    unsigned short* VIN = (unsigned short*)alloc((size_t)8192 * 64 * 2);
    __half* XW = (__half*)alloc((size_t)2 * 8192 * 1024 * 2);
    unsigned short* S_   = (unsigned short*)alloc((size_t)8192 * 512 * 2);
    unsigned short* HOUT = (unsigned short*)alloc((size_t)8192 * 512 * 2);
    __half* CONV = (__half*)VIN;   // reuse (dead by conv time)

    hipMemsetAsync(bC2W, 0, (size_t)128 * 512 * 2, stream);
    CastW cw;
    const float* srcs[9] = {vwihf, vwihb, vwhhf, vwhhb, hwihf, hwihb, hwhhf, hwhhb, c2w};
    unsigned short* dsts[9] = {bVWIHf, bVWIHb, bVWHHf, bVWHHb, bHWIHf, bHWIHb, bHWHHf, bHWHHb, bC2W};
    const int ns[9] = {65536, 65536, 262144, 262144, 524288, 524288, 262144, 262144, 32768};
    const int Ls[9] = {6, 6, 8, 8, 9, 9, 8, 8, 9};
    const int pm[9] = {1, 1, 1, 1, 1, 1, 1, 1, 0};
    for (int i = 0; i < 9; i++) { cw.src[i] = srcs[i]; cw.dst[i] = dsts[i]; cw.n[i] = ns[i]; cw.L[i] = Ls[i]; cw.perm[i] = pm[i]; }
    k_castw<<<dim3(2048, 9), 256, 0, stream>>>(cw);
    CastB cb;
    cb.src[0] = vbf; cb.dst[0] = pVBf;
    cb.src[1] = vbb; cb.dst[1] = pVBb;
    cb.src[2] = hbf; cb.dst[2] = pHBf;
    cb.src[3] = hbb; cb.dst[3] = pHBb;
    k_castb<<<dim3(4, 4), 256, 0, stream>>>(cb);

    const int SMs[3] = {256, 16, 1}, SAs[3] = {16, 256, 256}, SBs[3] = {1, 1, 16};
    for (int s = 0; s < 3; s++) {
        const float* Xin = (s == 0) ? x : ((s == 1) ? XA : XB);
        float* Xout = (s == 0) ? XA : ((s == 1) ? XB : XA);
        k_gather<<<512, 256, 0, stream>>>(Xin, VIN, SMs[s], SAs[s], SBs[s]);
        k_gemm<<<dim3(64, 8), 256, 0, stream>>>(VIN, 64, bVWIHf, pVBf, XW, 1024, 1024);
        k_gemm<<<dim3(64, 8), 256, 0, stream>>>(VIN, 64, bVWIHb, pVBb, XW + (size_t)8192 * 1024, 1024, 1024);
        k_scan<<<dim3(32, 2), 1024, 0, stream>>>(XW, bVWHHf, bVWHHb, S_, 0);
        k_gemm<<<dim3(64, 8), 256, 0, stream>>>(S_, 512, bHWIHf, pHBf, XW, 1024, 1024);
        k_gemm<<<dim3(64, 8), 256, 0, stream>>>(S_, 512, bHWIHb, pHBb, XW + (size_t)8192 * 1024, 1024, 1024);
        k_scan<<<dim3(32, 2), 1024, 0, stream>>>(XW, bHWHHf, bHWHHb, HOUT, 1);
        k_gemm<<<dim3(64, 1), 256, 0, stream>>>(HOUT, 512, bC2W, c2b, CONV, 64, 64);
        k_scatter<<<512, 256, 0, stream>>>(CONV, Xout, SMs[s], SAs[s], SBs[s]);
    }
    k_conv3<<<dim3(128, 2), 256, 0, stream>>>(XA, c3w, c3b, (float*)d_out);
}

// Round 4
// 652.047 us; speedup vs baseline: 2.5286x; 2.0051x over previous
//
#include <hip/hip_runtime.h>
#include <hip/hip_bf16.h>
#include <hip/hip_fp16.h>

// Renet3d. Matmuls: bf16 MFMA 16x16x32, fp32 accum.
// Scan v4: k-split pair scheme. Each (seq-tile, dir) is handled by TWO blocks (kh=0/1);
// each block keeps its 256 KB whh half fully register-resident (128 VGPR/wave of weights),
// exchanges its 16x128 h-half per step with its partner via device-scope atomics.
// Zero weight streaming in the recurrence loop.

typedef __attribute__((ext_vector_type(8))) short bf16x8;
typedef __attribute__((ext_vector_type(4))) float f32x4;
typedef __attribute__((ext_vector_type(4))) unsigned int u32x4;
typedef __attribute__((ext_vector_type(2))) unsigned int u32x2;

__device__ __forceinline__ unsigned short f2bf(float f) {
    unsigned int u = __float_as_uint(f);
    u += 0x7fffu + ((u >> 16) & 1u);
    return (unsigned short)(u >> 16);
}

// ---------------- weight casts: 9 jobs, optional gate-order row permutation ----------------
struct CastW { const float* src[9]; unsigned short* dst[9]; int n[9]; int L[9]; int perm[9]; };
__global__ void k_castw(CastW j) {
    const int a = blockIdx.y;
    const int i = blockIdx.x * 256 + threadIdx.x;
    if (i >= j.n[a]) return;
    const int L = j.L[a];
    const int r = i >> L, c = i & ((1 << L) - 1);
    const int dr = j.perm[a] ? ((r & 255) * 4 + (r >> 8)) : r;
    j.dst[a][(dr << L) | c] = f2bf(j.src[a][i]);
}
struct CastB { const float* src[4]; float* dst[4]; };
__global__ void k_castb(CastB j) {
    const int a = blockIdx.y;
    const int i = blockIdx.x * 256 + threadIdx.x;   // 0..1023
    j.dst[a][(i & 255) * 4 + (i >> 8)] = j.src[a][i];
}

// ---------------- gather: 5D f32 -> v_in bf16 [512*16][64] ----------------
__global__ void k_gather(const float* __restrict__ X, unsigned short* __restrict__ vin,
                         int sm, int sa, int sb) {
    const int seq = blockIdx.x;              // n*16+a
    const int n = seq >> 4, a = seq & 15;
    const size_t base = (size_t)(n >> 4) * 64 * 4096 + (size_t)sm * (n & 15) + (size_t)sa * a;
    for (int idx = threadIdx.x; idx < 1024; idx += 256) {
        const int c = idx & 63, b = idx >> 6;
        vin[((size_t)seq * 16 + b) * 64 + c] = f2bf(X[base + (size_t)c * 4096 + (size_t)sb * b]);
    }
}

// ---------------- GEMM: C[m][n](f16) = sum_k A[m][k]*W[n][k] + bias[n] ----------------
__global__ __launch_bounds__(256) void k_gemm(const unsigned short* __restrict__ A, int K,
        const unsigned short* __restrict__ W, const float* __restrict__ bias,
        __half* __restrict__ C, int ldc, int nvalid) {
    __shared__ unsigned short Alds[128 * 56];
    __shared__ unsigned short Blds[128 * 56];
    const int m0 = blockIdx.x * 128, n0 = blockIdx.y * 128;
    const int tid = threadIdx.x;
    const int lane = tid & 63, wid = tid >> 6;
    const int wr = wid >> 1, wc = wid & 1;
    const int fl = lane & 15, kk = (lane >> 4) * 8;
    f32x4 acc[4][4];
    #pragma unroll
    for (int mi = 0; mi < 4; mi++)
        #pragma unroll
        for (int ni = 0; ni < 4; ni++) { f32x4 z = {0.f,0.f,0.f,0.f}; acc[mi][ni] = z; }

    for (int k0 = 0; k0 < K; k0 += 32) {
        __syncthreads();
        #pragma unroll
        for (int h = 0; h < 2; h++) {
            const int cid = tid + h * 256;
            const int row = cid >> 2, c4 = cid & 3;
            *(u32x4*)&Alds[row * 56 + c4 * 8] = *(const u32x4*)(A + (size_t)(m0 + row) * K + k0 + c4 * 8);
            *(u32x4*)&Blds[row * 56 + c4 * 8] = *(const u32x4*)(W + (size_t)(n0 + row) * K + k0 + c4 * 8);
        }
        __syncthreads();
        bf16x8 af[4], bfb[4];
        #pragma unroll
        for (int i = 0; i < 4; i++) {
            af[i]  = *(const bf16x8*)&Alds[(wr * 64 + i * 16 + fl) * 56 + kk];
            bfb[i] = *(const bf16x8*)&Blds[(wc * 64 + i * 16 + fl) * 56 + kk];
        }
        #pragma unroll
        for (int mi = 0; mi < 4; mi++)
            #pragma unroll
            for (int ni = 0; ni < 4; ni++)
                acc[mi][ni] = __builtin_amdgcn_mfma_f32_16x16x32_bf16(af[mi], bfb[ni], acc[mi][ni], 0, 0, 0);
    }
    const int rl = (lane >> 4) * 4;
    #pragma unroll
    for (int ni = 0; ni < 4; ni++) {
        const int col = n0 + wc * 64 + ni * 16 + fl;
        if (col < nvalid) {
            const float bs = bias[col];
            #pragma unroll
            for (int mi = 0; mi < 4; mi++) {
                const int row = m0 + wr * 64 + mi * 16 + rl;
                #pragma unroll
                for (int j = 0; j < 4; j++)
                    C[(size_t)(row + j) * ldc + col] = __float2half(acc[mi][ni][j] + bs);
            }
        }
    }
}

// ---------------- LSTM scan v4: register-resident weights + pair exchange ----------------
// grid (32, 2, 2): x = seq-tile, y = dir, z = kh (k-half). 512 threads (8 waves).
// Block owns gate cols [kh*512, kh*512+512) (gate-reordered col' = 4k+g) == k in [kh*128, +128).
// Wave w owns cols [kh*512 + w*64, +64) == k in [kh*128 + w*16, +16).
// Weights: 4 nt x 8 kk bf16x8 = 128 VGPR per wave, loaded once.
// Per step: exchange own h-half (16 s x 128 k bf16 = 4 KB) with partner block via atomics.
__global__ __launch_bounds__(512, 2) void k_scan(const __half* __restrict__ xw,
        const unsigned short* __restrict__ whh_f, const unsigned short* __restrict__ whh_b,
        unsigned short* __restrict__ out, int out_mode,
        unsigned long long* __restrict__ HX, unsigned int* __restrict__ FLG, int phase) {
    __shared__ __align__(16) char gbuf[512 * 40];      // gates f16 [512 local cols][20 s-slots]
    __shared__ __align__(16) char hbuf[16 * 512];      // h bf16 [16 s][256 k], XOR-swizzled
    const int tid = threadIdx.x;
    const int lane = tid & 63, w = tid >> 6;
    const int fl = lane & 15, fh = lane >> 4;
    const int st = blockIdx.x, dir = blockIdx.y, kh = blockIdx.z;
    const int seq0 = st * 16;
    const unsigned short* whh_k = (dir ? whh_b : whh_f) + (size_t)kh * 512 * 256;
    const __half* xwd = xw + (size_t)dir * (8192 * 1024);
    const int C0g = kh * 512 + w * 64;     // global gate-col base for this wave
    const int slot = ((dir * 32 + st) * 2 + kh);
    unsigned long long* hx_me = HX + (size_t)slot * 512;
    unsigned long long* hx_p  = HX + (size_t)(slot ^ 1) * 512;
    unsigned int* flg_me = FLG + slot;
    unsigned int* flg_p  = FLG + (slot ^ 1);

    // zero hbuf (h(-1) = 0, both halves)
    #pragma unroll
    for (int i = 0; i < 4; i++) ((unsigned int*)hbuf)[tid + i * 512] = 0u;

    // weights -> registers (once): wave's 64 cols x 256 k
    bf16x8 wreg[4][8];
    #pragma unroll
    for (int nt = 0; nt < 4; nt++)
        #pragma unroll
        for (int kk = 0; kk < 8; kk++)
            wreg[nt][kk] = *(const bf16x8*)(whh_k + (size_t)(w * 64 + nt * 16 + fl) * 256 + kk * 32 + fh * 8);

    // nonlinearity ownership: thread -> k = kh*128 + w*16 + li, s = ls*4 + p (p=0..3)
    const int li = lane & 15, ls = lane >> 4;
    const int khalf = w * 16 + li;               // k index within this block's half [0,128)
    const int kglob = kh * 128 + khalf;
    float c_reg[4] = {0.f, 0.f, 0.f, 0.f};

    int tt = dir ? 15 : 0;
    const int tstep = dir ? -1 : 1;

    // prologue: xw C-operands for t=0 (elem (nt,j): seq row fh*4+j, col C0g+nt*16+fl)
    unsigned int xh[4][2];
    #pragma unroll
    for (int nt = 0; nt < 4; nt++)
        #pragma unroll
        for (int j2 = 0; j2 < 2; j2++) {
            const size_t base = ((size_t)(seq0 + fh * 4 + j2 * 2) * 16 + tt) * 1024 + C0g + nt * 16 + fl;
            const unsigned short h0 = __half_as_ushort(xwd[base]);
            const unsigned short h1 = __half_as_ushort(xwd[base + 16 * 1024]);
            xh[nt][j2] = (unsigned int)h0 | ((unsigned int)h1 << 16);
        }

    __syncthreads();

    for (int t = 0; t < 16; t++) {
        // ---- read phase: A-frags (full h(t-1)) + copy-out of h(t-1) own half ----
        bf16x8 afr[8];
        #pragma unroll
        for (int kk = 0; kk < 8; kk++) {
            const int ba = (fl * 512 + kk * 64 + fh * 16) ^ ((fl & 7) << 4);
            afr[kk] = *(const bf16x8*)(hbuf + ba);
        }
        if (t > 0) {
            const int ttp = tt - tstep;
            const int s = tid >> 5, q = tid & 31;
            const int ba = (s * 512 + (kh * 128 + q * 4) * 2) ^ ((s & 7) << 4);
            const u32x2 hv = *(const u32x2*)(hbuf + ba);
            const size_t row = out_mode ? ((size_t)(seq0 + s) * 16 + ttp)
                                        : ((size_t)st * 256 + (size_t)ttp * 16 + s);
            *(u32x2*)(out + row * 512 + dir * 256 + kh * 128 + q * 4) = hv;
        }
        __syncthreads();   // A: all hbuf reads done -> safe to overwrite

        // ---- MFMA from register weights ----
        #pragma unroll
        for (int nt = 0; nt < 4; nt++) {
            f32x4 acc;
            acc[0] = __half2float(__ushort_as_half((unsigned short)(xh[nt][0] & 0xffff)));
            acc[1] = __half2float(__ushort_as_half((unsigned short)(xh[nt][0] >> 16)));
            acc[2] = __half2float(__ushort_as_half((unsigned short)(xh[nt][1] & 0xffff)));
            acc[3] = __half2float(__ushort_as_half((unsigned short)(xh[nt][1] >> 16)));
            #pragma unroll
            for (int kk = 0; kk < 8; kk++)
                acc = __builtin_amdgcn_mfma_f32_16x16x32_bf16(afr[kk], wreg[nt][kk], acc, 0, 0, 0);
            const int coll = w * 64 + nt * 16 + fl;       // local col
            const unsigned int lo = (unsigned int)__half_as_ushort(__float2half(acc[0])) |
                                    ((unsigned int)__half_as_ushort(__float2half(acc[1])) << 16);
            const unsigned int hi = (unsigned int)__half_as_ushort(__float2half(acc[2])) |
                                    ((unsigned int)__half_as_ushort(__float2half(acc[3])) << 16);
            u32x2 pk = {lo, hi};
            *(u32x2*)(gbuf + coll * 40 + fh * 8) = pk;    // [col][s] f16, s = fh*4..+4
        }

        // ---- prefetch next step's xw (overlaps nonlin + sync) ----
        const int tn = (t < 15) ? tt + tstep : tt;
        #pragma unroll
        for (int nt = 0; nt < 4; nt++)
            #pragma unroll
            for (int j2 = 0; j2 < 2; j2++) {
                const size_t base = ((size_t)(seq0 + fh * 4 + j2 * 2) * 16 + tn) * 1024 + C0g + nt * 16 + fl;
                const unsigned short h0 = __half_as_ushort(xwd[base]);
                const unsigned short h1 = __half_as_ushort(xwd[base + 16 * 1024]);
                xh[nt][j2] = (unsigned int)h0 | ((unsigned int)h1 << 16);
            }

        // ---- nonlinearity (wave-local gbuf cols; no barrier needed) ----
        float gv[4][4];
        const int colbase = w * 64 + 4 * li;
        #pragma unroll
        for (int g = 0; g < 4; g++) {
            const u32x2 a = *(const u32x2*)(gbuf + (colbase + g) * 40 + ls * 8);
            gv[g][0] = __half2float(__ushort_as_half((unsigned short)(a[0] & 0xffff)));
            gv[g][1] = __half2float(__ushort_as_half((unsigned short)(a[0] >> 16)));
            gv[g][2] = __half2float(__ushort_as_half((unsigned short)(a[1] & 0xffff)));
            gv[g][3] = __half2float(__ushort_as_half((unsigned short)(a[1] >> 16)));
        }
        unsigned long long hpack = 0ull;
        #pragma unroll
        for (int p = 0; p < 4; p++) {
            const float ig = 1.f / (1.f + __expf(-gv[0][p]));
            const float fg = 1.f / (1.f + __expf(-gv[1][p]));
            const float e2 = __expf(2.f * gv[2][p]);
            const float gg = 1.f - 2.f / (e2 + 1.f);
            const float og = 1.f / (1.f + __expf(-gv[3][p]));
            const float c = fg * c_reg[p] + ig * gg;
            c_reg[p] = c;
            const float e2c = __expf(2.f * c);
            const float hv = og * (1.f - 2.f / (e2c + 1.f));
            const unsigned short hb = f2bf(hv);
            const int s = ls * 4 + p;
            *(unsigned short*)(hbuf + ((s * 512 + kglob * 2) ^ ((s & 7) << 4))) = hb;
            hpack |= ((unsigned long long)hb) << (16 * p);
        }

        if (t < 15) {
            // publish own h-half: hx_me[khalf*4 + ls] covers s = ls*4..+4
            atomicExch(&hx_me[khalf * 4 + ls], hpack);
            asm volatile("s_waitcnt vmcnt(0)" ::: "memory");   // data acked at coherence point
            __syncthreads();                                    // B: all waves' data out
            const unsigned int want = (unsigned int)(phase * 16 + t + 1);
            if (tid == 0) {
                atomicExch(flg_me, want);
                while (atomicAdd(flg_p, 0u) < want) __builtin_amdgcn_s_sleep(1);
            }
            __syncthreads();                                    // C: partner data ready
            // pull partner half: thread tid -> u64 idx tid: k' = tid>>2, s' = (tid&3)*4..+4
            const unsigned long long pv = atomicAdd(&hx_p[tid], 0ull);
            const int kp = (1 - kh) * 128 + (tid >> 2);
            const int sp0 = (tid & 3) * 4;
            #pragma unroll
            for (int e = 0; e < 4; e++) {
                const int s = sp0 + e;
                *(unsigned short*)(hbuf + ((s * 512 + kp * 2) ^ ((s & 7) << 4))) =
                    (unsigned short)(pv >> (16 * e));
            }
        }
        tt = tn;
        __syncthreads();   // D: hbuf(t) complete
    }
    // epilogue: copy-out h(15) own half
    {
        const int s = tid >> 5, q = tid & 31;
        const int ba = (s * 512 + (kh * 128 + q * 4) * 2) ^ ((s & 7) << 4);
        const u32x2 hv = *(const u32x2*)(hbuf + ba);
        const size_t row = out_mode ? ((size_t)(seq0 + s) * 16 + tt)
                                    : ((size_t)st * 256 + (size_t)tt * 16 + s);
        *(u32x2*)(out + row * 512 + dir * 256 + kh * 128 + q * 4) = hv;
    }
}

// ---------------- conv2 scatter: f16 conv output -> 5D f32 ----------------
__global__ void k_scatter(const __half* __restrict__ conv, float* __restrict__ Xout,
                          int sm, int sa, int sb) {
    const int blk = blockIdx.x;
    const int n = blk >> 4, a = blk & 15;
    const size_t base = (size_t)(n >> 4) * 64 * 4096 + (size_t)sm * (n & 15) + (size_t)sa * a;
    for (int idx = threadIdx.x; idx < 1024; idx += 256) {
        const int b = idx & 15, o = idx >> 4;
        Xout[base + (size_t)o * 4096 + (size_t)sb * b] =
            __half2float(conv[((size_t)(n * 16 + b) * 16 + a) * 64 + o]);
    }
}

// ---------------- final conv3d 1x1x1 (f32 vector) ----------------
__global__ __launch_bounds__(256) void k_conv3(const float* __restrict__ X,
        const float* __restrict__ w, const float* __restrict__ bias, float* __restrict__ out) {
    __shared__ float xl[64 * 32];
    __shared__ float wl[64 * 64];
    const int bb = blockIdx.y;
    const int p0 = blockIdx.x * 32;
    const int tid = threadIdx.x;
    for (int i = tid; i < 64 * 32; i += 256) {
        const int c = i >> 5, pp = i & 31;
        xl[i] = X[((size_t)bb * 64 + c) * 4096 + p0 + pp];
    }
    for (int i = tid; i < 64 * 64; i += 256) wl[i] = w[i];
    __syncthreads();
    const int pp = tid & 31, og = tid >> 5;
    #pragma unroll
    for (int oj = 0; oj < 8; oj++) {
        const int o = og * 8 + oj;
        float acc = bias[o];
        #pragma unroll 16
        for (int c = 0; c < 64; c++) acc += xl[c * 32 + pp] * wl[o * 64 + c];
        out[((size_t)bb * 64 + o) * 4096 + p0 + pp] = acc;
    }
}

extern "C" void kernel_launch(void* const* d_in, const int* in_sizes, int n_in,
                              void* d_out, int out_size, void* d_ws, size_t ws_size,
                              hipStream_t stream) {
    (void)in_sizes; (void)n_in; (void)out_size; (void)ws_size;
    const float* x     = (const float*)d_in[0];
    const float* vwihf = (const float*)d_in[1];
    const float* vwhhf = (const float*)d_in[2];
    const float* vbf   = (const float*)d_in[3];
    const float* vwihb = (const float*)d_in[4];
    const float* vwhhb = (const float*)d_in[5];
    const float* vbb   = (const float*)d_in[6];
    const float* hwihf = (const float*)d_in[7];
    const float* hwhhf = (const float*)d_in[8];
    const float* hbf   = (const float*)d_in[9];
    const float* hwihb = (const float*)d_in[10];
    const float* hwhhb = (const float*)d_in[11];
    const float* hbb   = (const float*)d_in[12];
    const float* c2w   = (const float*)d_in[13];
    const float* c2b   = (const float*)d_in[14];
    const float* c3w   = (const float*)d_in[15];
    const float* c3b   = (const float*)d_in[16];

    char* p = (char*)d_ws;
    auto alloc = [&](size_t bytes) { char* r = p; p += (bytes + 255) & ~((size_t)255); return r; };
    unsigned short* bVWIHf = (unsigned short*)alloc((size_t)1024 * 64 * 2);
    unsigned short* bVWIHb = (unsigned short*)alloc((size_t)1024 * 64 * 2);
    unsigned short* bVWHHf = (unsigned short*)alloc((size_t)1024 * 256 * 2);
    unsigned short* bVWHHb = (unsigned short*)alloc((size_t)1024 * 256 * 2);
    unsigned short* bHWIHf = (unsigned short*)alloc((size_t)1024 * 512 * 2);
    unsigned short* bHWIHb = (unsigned short*)alloc((size_t)1024 * 512 * 2);
    unsigned short* bHWHHf = (unsigned short*)alloc((size_t)1024 * 256 * 2);
    unsigned short* bHWHHb = (unsigned short*)alloc((size_t)1024 * 256 * 2);
    unsigned short* bC2W   = (unsigned short*)alloc((size_t)128 * 512 * 2);
    float* pVBf = (float*)alloc(1024 * 4);
    float* pVBb = (float*)alloc(1024 * 4);
    float* pHBf = (float*)alloc(1024 * 4);
    float* pHBb = (float*)alloc(1024 * 4);
    unsigned long long* HX = (unsigned long long*)alloc((size_t)128 * 4096);
    unsigned int* FLG = (unsigned int*)alloc(512);
    float* XA = (float*)alloc((size_t)524288 * 4);
    float* XB = (float*)alloc((size_t)524288 * 4);
    unsigned short* VIN = (unsigned short*)alloc((size_t)8192 * 64 * 2);
    __half* XW = (__half*)alloc((size_t)2 * 8192 * 1024 * 2);
    unsigned short* S_   = (unsigned short*)alloc((size_t)8192 * 512 * 2);
    unsigned short* HOUT = (unsigned short*)alloc((size_t)8192 * 512 * 2);
    __half* CONV = (__half*)VIN;   // reuse (dead by conv time)

    hipMemsetAsync(bC2W, 0, (size_t)128 * 512 * 2, stream);
    hipMemsetAsync(FLG, 0, 512, stream);   // flag epoch reset once per launch (graph-replay safe)
    CastW cw;
    const float* srcs[9] = {vwihf, vwihb, vwhhf, vwhhb, hwihf, hwihb, hwhhf, hwhhb, c2w};
    unsigned short* dsts[9] = {bVWIHf, bVWIHb, bVWHHf, bVWHHb, bHWIHf, bHWIHb, bHWHHf, bHWHHb, bC2W};
    const int ns[9] = {65536, 65536, 262144, 262144, 524288, 524288, 262144, 262144, 32768};
    const int Ls[9] = {6, 6, 8, 8, 9, 9, 8, 8, 9};
    const int pm[9] = {1, 1, 1, 1, 1, 1, 1, 1, 0};
    for (int i = 0; i < 9; i++) { cw.src[i] = srcs[i]; cw.dst[i] = dsts[i]; cw.n[i] = ns[i]; cw.L[i] = Ls[i]; cw.perm[i] = pm[i]; }
    k_castw<<<dim3(2048, 9), 256, 0, stream>>>(cw);
    CastB cb;
    cb.src[0] = vbf; cb.dst[0] = pVBf;
    cb.src[1] = vbb; cb.dst[1] = pVBb;
    cb.src[2] = hbf; cb.dst[2] = pHBf;
    cb.src[3] = hbb; cb.dst[3] = pHBb;
    k_castb<<<dim3(4, 4), 256, 0, stream>>>(cb);

    const int SMs[3] = {256, 16, 1}, SAs[3] = {16, 256, 256}, SBs[3] = {1, 1, 16};
    for (int s = 0; s < 3; s++) {
        const float* Xin = (s == 0) ? x : ((s == 1) ? XA : XB);
        float* Xout = (s == 0) ? XA : ((s == 1) ? XB : XA);
        k_gather<<<512, 256, 0, stream>>>(Xin, VIN, SMs[s], SAs[s], SBs[s]);
        k_gemm<<<dim3(64, 8), 256, 0, stream>>>(VIN, 64, bVWIHf, pVBf, XW, 1024, 1024);
        k_gemm<<<dim3(64, 8), 256, 0, stream>>>(VIN, 64, bVWIHb, pVBb, XW + (size_t)8192 * 1024, 1024, 1024);
        k_scan<<<dim3(32, 2, 2), 512, 0, stream>>>(XW, bVWHHf, bVWHHb, S_, 0, HX, FLG, s * 2 + 0);
        k_gemm<<<dim3(64, 8), 256, 0, stream>>>(S_, 512, bHWIHf, pHBf, XW, 1024, 1024);
        k_gemm<<<dim3(64, 8), 256, 0, stream>>>(S_, 512, bHWIHb, pHBb, XW + (size_t)8192 * 1024, 1024, 1024);
        k_scan<<<dim3(32, 2, 2), 512, 0, stream>>>(XW, bHWHHf, bHWHHb, HOUT, 1, HX, FLG, s * 2 + 1);
        k_gemm<<<dim3(64, 1), 256, 0, stream>>>(HOUT, 512, bC2W, c2b, CONV, 64, 64);
        k_scatter<<<512, 256, 0, stream>>>(CONV, Xout, SMs[s], SAs[s], SBs[s]);
    }
    k_conv3<<<dim3(128, 2), 256, 0, stream>>>(XA, c3w, c3b, (float*)d_out);
}